// Round 2
// baseline (305.408 us; speedup 1.0000x reference)
//
#include <hip/hip_runtime.h>
#include <hip/hip_bf16.h>

#define DEV static __device__ __forceinline__

typedef __attribute__((ext_vector_type(8))) short bf16x8;          // 8 bf16 (4 VGPRs)
typedef __attribute__((ext_vector_type(8))) unsigned short u16x8;  // raw 16B chunk
typedef __attribute__((ext_vector_type(4))) float f32x4;

constexpr int Bn = 8, Tn = 2048, DMn = 1024, DKn = 128;

DEV unsigned short f2bf(float f) {
  union { float f; unsigned u; } c; c.f = f;
  unsigned u = c.u;
  unsigned r = (u + 0x7fffu + ((u >> 16) & 1u)) >> 16;  // RNE
  return (unsigned short)r;
}

// ---------------- fp32 -> bf16 convert (vectorized, grid-stride) ----------------
__global__ void cvt_f32_to_bf16(const float* __restrict__ in,
                                unsigned short* __restrict__ out, int n) {
  int stride = gridDim.x * blockDim.x;
  for (int i = blockIdx.x * blockDim.x + threadIdx.x; i * 4 < n; i += stride) {
    float4 v = *reinterpret_cast<const float4*>(in + (size_t)i * 4);
    ushort4 o;
    o.x = f2bf(v.x); o.y = f2bf(v.y); o.z = f2bf(v.z); o.w = f2bf(v.w);
    *reinterpret_cast<ushort4*>(out + (size_t)i * 4) = o;
  }
}

// ---------------- QKV projection: C[m][n] = sum_k X[m][k] * W[n][k] ----------------
// 128x128 tile, BK=64, 4 waves (2x2), each wave 64x64 = 4x4 frags of 16x16x32 bf16 MFMA.
__global__ __launch_bounds__(256) void qkv_proj(
    const unsigned short* __restrict__ X,   // [16384][1024] bf16
    const unsigned short* __restrict__ W3,  // [3][128][1024] bf16
    unsigned short* __restrict__ Q,
    unsigned short* __restrict__ K,
    unsigned short* __restrict__ V) {
  constexpr int BK = 64;
  __shared__ __align__(16) unsigned short Al[128 * BK];
  __shared__ __align__(16) unsigned short Bl[128 * BK];
  const int g = blockIdx.y;
  const int m0 = blockIdx.x * 128;
  const unsigned short* Wg = W3 + (size_t)g * 128 * 1024;
  unsigned short* Out = (g == 0) ? Q : (g == 1) ? K : V;
  const float scale = (g == 0) ? 0.08838834764831845f : 1.0f;  // 1/sqrt(128) folded into Q

  const int tid = threadIdx.x;
  const int lane = tid & 63;
  const int wid = tid >> 6;
  const int wm = wid >> 1;
  const int wn = wid & 1;

  f32x4 acc[4][4] = {};

  for (int k0 = 0; k0 < DMn; k0 += BK) {
    __syncthreads();
    // stage A (X tile) and B (W rows) : each 128x64 bf16 = 16KB, linear row-major
#pragma unroll
    for (int it = 0; it < 4; ++it) {
      int ch = it * 256 + tid;           // 0..1023, 16B chunk id
      int row = ch >> 3;
      int col = (ch & 7) * 8;
      *reinterpret_cast<u16x8*>(&Al[ch * 8]) =
          *reinterpret_cast<const u16x8*>(&X[(size_t)(m0 + row) * DMn + k0 + col]);
      *reinterpret_cast<u16x8*>(&Bl[ch * 8]) =
          *reinterpret_cast<const u16x8*>(&Wg[(size_t)row * DMn + k0 + col]);
    }
    __syncthreads();
#pragma unroll
    for (int kk = 0; kk < 2; ++kk) {
      const int lrow = lane & 15;
      const int lcol = kk * 32 + (lane >> 4) * 8;
      bf16x8 af[4], bfr[4];
#pragma unroll
      for (int mf = 0; mf < 4; ++mf)
        af[mf] = *reinterpret_cast<const bf16x8*>(&Al[(wm * 64 + mf * 16 + lrow) * BK + lcol]);
#pragma unroll
      for (int nf = 0; nf < 4; ++nf)
        bfr[nf] = *reinterpret_cast<const bf16x8*>(&Bl[(wn * 64 + nf * 16 + lrow) * BK + lcol]);
#pragma unroll
      for (int mf = 0; mf < 4; ++mf)
#pragma unroll
        for (int nf = 0; nf < 4; ++nf)
          acc[mf][nf] = __builtin_amdgcn_mfma_f32_16x16x32_bf16(af[mf], bfr[nf], acc[mf][nf], 0, 0, 0);
    }
  }
  // epilogue: D layout col=lane&15, row=(lane>>4)*4+r  [measured m89]
#pragma unroll
  for (int mf = 0; mf < 4; ++mf)
#pragma unroll
    for (int nf = 0; nf < 4; ++nf)
#pragma unroll
      for (int r = 0; r < 4; ++r) {
        int m = m0 + wm * 64 + mf * 16 + (lane >> 4) * 4 + r;
        int n = wn * 64 + nf * 16 + (lane & 15);
        Out[(size_t)m * DKn + n] = f2bf(acc[mf][nf][r] * scale);
      }
}

// ---------------- causal flash attention ----------------
// block = (64 Q rows, one batch); 4 waves x 16 rows; KVBLK=32.
__global__ __launch_bounds__(256) void attn(
    const unsigned short* __restrict__ Qg,
    const unsigned short* __restrict__ Kg,
    const unsigned short* __restrict__ Vg,
    float* __restrict__ Out) {
  const int b = blockIdx.y;
  const int qb = blockIdx.x;
  const int q0 = qb * 64;
  const int lane = threadIdx.x & 63;
  const int wid = threadIdx.x >> 6;
  const unsigned short* Qb = Qg + (size_t)b * Tn * DKn;
  const unsigned short* Kb = Kg + (size_t)b * Tn * DKn;
  const unsigned short* Vb = Vg + (size_t)b * Tn * DKn;

  __shared__ __align__(16) unsigned short Vt[128][40];    // V tile transposed [d][s], padded
  __shared__ __align__(16) unsigned short Pl[4][16][40];  // per-wave P round-trip, padded

  // Q fragments in registers (pre-scaled by 1/sqrt(128) at projection)
  bf16x8 qf[4];
  {
    const int qrow = q0 + wid * 16 + (lane & 15);
    const int c0 = (lane >> 4) * 8;
#pragma unroll
    for (int c = 0; c < 4; ++c)
      qf[c] = *reinterpret_cast<const bf16x8*>(&Qb[(size_t)qrow * DKn + c * 32 + c0]);
  }

  f32x4 o[8] = {};
  float mrow[4] = {-1e30f, -1e30f, -1e30f, -1e30f};
  float lrow[4] = {0.f, 0.f, 0.f, 0.f};

  const int nj = 2 * qb + 2;  // KV blocks of 32 up to and including the diagonal
  for (int j = 0; j < nj; ++j) {
    const int s0 = j * 32;
    __syncthreads();
    // stage V tile transposed: Vt[d][s] = V[s0+s][d]
#pragma unroll
    for (int c = 0; c < 2; ++c) {
      int idx = ((int)threadIdx.x * 2 + c) * 8;  // 0..4088
      int s = idx >> 7;
      int d0 = idx & 127;
      u16x8 v = *reinterpret_cast<const u16x8*>(&Vb[(size_t)(s0 + s) * DKn + d0]);
#pragma unroll
      for (int jj = 0; jj < 8; ++jj) Vt[d0 + jj][s] = (unsigned short)v[jj];
    }
    __syncthreads();

    // S = Q K^T  (two 16-col tiles), K B-frags straight from global (L2-resident)
    f32x4 sacc[2] = {};
    const int c0 = (lane >> 4) * 8;
#pragma unroll
    for (int nt = 0; nt < 2; ++nt) {
      const size_t krow = (size_t)(s0 + nt * 16 + (lane & 15)) * DKn;
#pragma unroll
      for (int kc = 0; kc < 4; ++kc) {
        bf16x8 kf = *reinterpret_cast<const bf16x8*>(&Kb[krow + kc * 32 + c0]);
        sacc[nt] = __builtin_amdgcn_mfma_f32_16x16x32_bf16(qf[kc], kf, sacc[nt], 0, 0, 0);
      }
    }

    // causal mask + online softmax (rows live in D layout: row=(lane>>4)*4+r, col=lane&15)
    const int rowbase = q0 + wid * 16 + (lane >> 4) * 4;
    float pv[2][4];
    float pmax[4] = {-1e30f, -1e30f, -1e30f, -1e30f};
#pragma unroll
    for (int nt = 0; nt < 2; ++nt) {
      const int s = s0 + nt * 16 + (lane & 15);
#pragma unroll
      for (int r = 0; r < 4; ++r) {
        float v = (s <= rowbase + r) ? sacc[nt][r] : -1e30f;
        pv[nt][r] = v;
        pmax[r] = fmaxf(pmax[r], v);
      }
    }
#pragma unroll
    for (int r = 0; r < 4; ++r) {
      float m = pmax[r];
      m = fmaxf(m, __shfl_xor(m, 1));
      m = fmaxf(m, __shfl_xor(m, 2));
      m = fmaxf(m, __shfl_xor(m, 4));
      m = fmaxf(m, __shfl_xor(m, 8));
      float mnew = fmaxf(mrow[r], m);
      float f = __expf(mrow[r] - mnew);
      mrow[r] = mnew;
      float ps = 0.f;
#pragma unroll
      for (int nt = 0; nt < 2; ++nt) {
        float p = __expf(pv[nt][r] - mnew);
        pv[nt][r] = p;
        ps += p;
      }
      ps += __shfl_xor(ps, 1);
      ps += __shfl_xor(ps, 2);
      ps += __shfl_xor(ps, 4);
      ps += __shfl_xor(ps, 8);
      lrow[r] = lrow[r] * f + ps;
#pragma unroll
      for (int n = 0; n < 8; ++n) o[n][r] *= f;
    }

    // P: D layout -> A layout via per-wave LDS round-trip (bf16)
#pragma unroll
    for (int nt = 0; nt < 2; ++nt)
#pragma unroll
      for (int r = 0; r < 4; ++r)
        Pl[wid][(lane >> 4) * 4 + r][nt * 16 + (lane & 15)] = f2bf(pv[nt][r]);
    bf16x8 pf = *reinterpret_cast<const bf16x8*>(&Pl[wid][lane & 15][(lane >> 4) * 8]);

    // O += P V : 8 col tiles, V B-frags from transposed LDS (contiguous b128)
#pragma unroll
    for (int n = 0; n < 8; ++n) {
      bf16x8 vf = *reinterpret_cast<const bf16x8*>(&Vt[n * 16 + (lane & 15)][(lane >> 4) * 8]);
      o[n] = __builtin_amdgcn_mfma_f32_16x16x32_bf16(pf, vf, o[n], 0, 0, 0);
    }
  }

  // epilogue: normalize and store fp32
#pragma unroll
  for (int n = 0; n < 8; ++n)
#pragma unroll
    for (int r = 0; r < 4; ++r) {
      int t = q0 + wid * 16 + (lane >> 4) * 4 + r;
      int d = n * 16 + (lane & 15);
      Out[((size_t)b * Tn + t) * DKn + d] = o[n][r] / lrow[r];
    }
}

extern "C" void kernel_launch(void* const* d_in, const int* in_sizes, int n_in,
                              void* d_out, int out_size, void* d_ws, size_t ws_size,
                              hipStream_t stream) {
  const float* x  = (const float*)d_in[0];
  const float* Wq = (const float*)d_in[1];
  const float* Wk = (const float*)d_in[2];
  const float* Wv = (const float*)d_in[3];
  float* out = (float*)d_out;

  unsigned short* ws = (unsigned short*)d_ws;
  unsigned short* Xb = ws;                                   // 16384*1024
  unsigned short* Wb = Xb + (size_t)16384 * 1024;            // 3*128*1024
  unsigned short* Qw = Wb + (size_t)3 * 128 * 1024;          // 16384*128
  unsigned short* Kw = Qw + (size_t)16384 * 128;
  unsigned short* Vw = Kw + (size_t)16384 * 128;

  cvt_f32_to_bf16<<<4096, 256, 0, stream>>>(x, Xb, 16384 * 1024);
  cvt_f32_to_bf16<<<128, 256, 0, stream>>>(Wq, Wb, 128 * 1024);
  cvt_f32_to_bf16<<<128, 256, 0, stream>>>(Wk, Wb + 128 * 1024, 128 * 1024);
  cvt_f32_to_bf16<<<128, 256, 0, stream>>>(Wv, Wb + 2 * 128 * 1024, 128 * 1024);

  qkv_proj<<<dim3(128, 3), 256, 0, stream>>>(Xb, Wb, Qw, Kw, Vw);
  attn<<<dim3(32, 8), 256, 0, stream>>>(Qw, Kw, Vw, out);
}

// Round 3
// 265.906 us; speedup vs baseline: 1.1486x; 1.1486x over previous
//
#include <hip/hip_runtime.h>
#include <hip/hip_bf16.h>

#define DEV static __device__ __forceinline__

typedef __attribute__((ext_vector_type(8))) short bf16x8;          // 8 bf16 (4 VGPRs)
typedef __attribute__((ext_vector_type(8))) unsigned short u16x8;  // raw 16B chunk
typedef __attribute__((ext_vector_type(4))) float f32x4;

constexpr int Bn = 8, Tn = 2048, DMn = 1024, DKn = 128;

DEV unsigned short f2bf(float f) {
  union { float f; unsigned u; } c; c.f = f;
  unsigned u = c.u;
  unsigned r = (u + 0x7fffu + ((u >> 16) & 1u)) >> 16;  // RNE
  return (unsigned short)r;
}

// ---------------- fp32 -> bf16 convert: x + 3 weights in ONE launch ----------------
__global__ void cvt_all(const float* __restrict__ x,  const float* __restrict__ wq,
                        const float* __restrict__ wk, const float* __restrict__ wv,
                        unsigned short* __restrict__ Xb, unsigned short* __restrict__ Wb) {
  constexpr int NX = 16384 * 1024 / 4;  // float4 chunks of x
  constexpr int NW = 131072 / 4;        // float4 chunks per W
  const int total = NX + 3 * NW;
  const int stride = gridDim.x * blockDim.x;
  for (int i = blockIdx.x * blockDim.x + threadIdx.x; i < total; i += stride) {
    const float* src; unsigned short* dst; int off;
    if (i < NX) { src = x; dst = Xb; off = i; }
    else {
      int j = i - NX; int w = j >> 15; off = j & (NW - 1);
      src = (w == 0) ? wq : (w == 1) ? wk : wv;
      dst = Wb + (size_t)w * 131072;
    }
    float4 v = *reinterpret_cast<const float4*>(src + (size_t)off * 4);
    ushort4 o;
    o.x = f2bf(v.x); o.y = f2bf(v.y); o.z = f2bf(v.z); o.w = f2bf(v.w);
    *reinterpret_cast<ushort4*>(dst + (size_t)off * 4) = o;
  }
}

// ---------------- QKV projection: C[m][n] = sum_k X[m][k] * W[n][k] ----------------
// 128x128 tile, BK=64, 4 waves (2x2), each wave 64x64 = 4x4 frags of 16x16x32 bf16 MFMA.
__global__ __launch_bounds__(256) void qkv_proj(
    const unsigned short* __restrict__ X,   // [16384][1024] bf16
    const unsigned short* __restrict__ W3,  // [3][128][1024] bf16
    unsigned short* __restrict__ Q,
    unsigned short* __restrict__ K,
    unsigned short* __restrict__ V) {
  constexpr int BK = 64;
  __shared__ __align__(16) unsigned short Al[128 * BK];
  __shared__ __align__(16) unsigned short Bl[128 * BK];
  const int g = blockIdx.y;
  const int m0 = blockIdx.x * 128;
  const unsigned short* Wg = W3 + (size_t)g * 128 * 1024;
  unsigned short* Out = (g == 0) ? Q : (g == 1) ? K : V;
  const float scale = (g == 0) ? 0.08838834764831845f : 1.0f;  // 1/sqrt(128) folded into Q

  const int tid = threadIdx.x;
  const int lane = tid & 63;
  const int wid = tid >> 6;
  const int wm = wid >> 1;
  const int wn = wid & 1;

  f32x4 acc[4][4] = {};

  for (int k0 = 0; k0 < DMn; k0 += BK) {
    __syncthreads();
#pragma unroll
    for (int it = 0; it < 4; ++it) {
      int ch = it * 256 + tid;           // 0..1023, 16B chunk id
      int row = ch >> 3;
      int col = (ch & 7) * 8;
      *reinterpret_cast<u16x8*>(&Al[ch * 8]) =
          *reinterpret_cast<const u16x8*>(&X[(size_t)(m0 + row) * DMn + k0 + col]);
      *reinterpret_cast<u16x8*>(&Bl[ch * 8]) =
          *reinterpret_cast<const u16x8*>(&Wg[(size_t)row * DMn + k0 + col]);
    }
    __syncthreads();
#pragma unroll
    for (int kk = 0; kk < 2; ++kk) {
      const int lrow = lane & 15;
      const int lcol = kk * 32 + (lane >> 4) * 8;
      bf16x8 af[4], bfr[4];
#pragma unroll
      for (int mf = 0; mf < 4; ++mf)
        af[mf] = *reinterpret_cast<const bf16x8*>(&Al[(wm * 64 + mf * 16 + lrow) * BK + lcol]);
#pragma unroll
      for (int nf = 0; nf < 4; ++nf)
        bfr[nf] = *reinterpret_cast<const bf16x8*>(&Bl[(wn * 64 + nf * 16 + lrow) * BK + lcol]);
#pragma unroll
      for (int mf = 0; mf < 4; ++mf)
#pragma unroll
        for (int nf = 0; nf < 4; ++nf)
          acc[mf][nf] = __builtin_amdgcn_mfma_f32_16x16x32_bf16(af[mf], bfr[nf], acc[mf][nf], 0, 0, 0);
    }
  }
#pragma unroll
  for (int mf = 0; mf < 4; ++mf)
#pragma unroll
    for (int nf = 0; nf < 4; ++nf)
#pragma unroll
      for (int r = 0; r < 4; ++r) {
        int m = m0 + wm * 64 + mf * 16 + (lane >> 4) * 4 + r;
        int n = wn * 64 + nf * 16 + (lane & 15);
        Out[(size_t)m * DKn + n] = f2bf(acc[mf][nf][r] * scale);
      }
}

// ---------------- causal flash attention, balanced ----------------
// block = (32 Q-rows, one batch), 8 waves = 2 row-groups x 4-way KV split.
// Each super-iter stages 128 KV rows of V (transposed+swizzled); wave (rg,kp)
// processes KV-block (siter*4+kp) for its 16 rows. Private (m,l,o) partials,
// merged in-LDS at the end. Grid x reversed so longest tiles dispatch first (LPT).
__global__ __launch_bounds__(512) void attn(
    const unsigned short* __restrict__ Qg,
    const unsigned short* __restrict__ Kg,
    const unsigned short* __restrict__ Vg,
    float* __restrict__ Out) {
  const int b = blockIdx.y;
  const int t = 63 - blockIdx.x;          // LPT: longest tile first
  const int q0 = t * 32;
  const int tid = threadIdx.x;
  const int lane = tid & 63;
  const int wid = tid >> 6;               // 0..7
  const int rg = wid >> 2;                // row group (16 rows each)
  const int kp = wid & 3;                 // KV parity
  const int nb = t + 1;                   // 32-wide KV blocks in causal range
  const int nsuper = (nb + 3) >> 2;

  const unsigned short* Qb = Qg + (size_t)b * Tn * DKn;
  const unsigned short* Kb = Kg + (size_t)b * Tn * DKn;
  const unsigned short* Vb = Vg + (size_t)b * Tn * DKn;

  __shared__ __align__(16) unsigned short Vt[128][136];   // V^T staged, s-group swizzled (34.8KB; reused as Om)
  __shared__ __align__(16) unsigned short Pl[8][16][40];  // per-wave P round-trip
  __shared__ float Ml[8][16][2];                          // per-wave (m,l) for merge

  // Q fragments (pre-scaled by 1/sqrt(128) at projection)
  bf16x8 qf[4];
  {
    const int qrow = q0 + rg * 16 + (lane & 15);
    const int c0 = (lane >> 4) * 8;
#pragma unroll
    for (int c = 0; c < 4; ++c)
      qf[c] = *reinterpret_cast<const bf16x8*>(&Qb[(size_t)qrow * DKn + c * 32 + c0]);
  }

  f32x4 o[8] = {};
  float mrow[4] = {-1e30f, -1e30f, -1e30f, -1e30f};
  float lrow[4] = {0.f, 0.f, 0.f, 0.f};

  for (int siter = 0; siter < nsuper; ++siter) {
    const int sbase = siter * 128;
    __syncthreads();
    // stage V^T for 128 KV rows: Vt[d][swz(s)] = V[sbase+s][d]
    // swizzle: col = (((s>>3) ^ (d>>3)) & 15)*8 + (s&7)  -> write conflicts 16-way -> 2-way
#pragma unroll
    for (int k = 0; k < 4; ++k) {
      int c = k * 512 + tid;          // 2048 chunks of 8 d-values
      int s = c >> 4;
      int d0 = (c & 15) * 8;
      u16x8 v = *reinterpret_cast<const u16x8*>(&Vb[(size_t)(sbase + s) * DKn + d0]);
#pragma unroll
      for (int jj = 0; jj < 8; ++jj) {
        int d = d0 + jj;
        int col = ((((s >> 3) ^ (d >> 3)) & 15) << 3) | (s & 7);
        Vt[d][col] = (unsigned short)v[jj];
      }
    }
    __syncthreads();

    const int j = siter * 4 + kp;
    if (j < nb) {
      const int s0j = j * 32;
      // S = Q K^T (16 rows x 32 KV), K B-frags from global (L2-resident)
      f32x4 sacc[2] = {};
      const int c0 = (lane >> 4) * 8;
#pragma unroll
      for (int nt = 0; nt < 2; ++nt) {
        const size_t krow = (size_t)(s0j + nt * 16 + (lane & 15)) * DKn;
#pragma unroll
        for (int kc = 0; kc < 4; ++kc) {
          bf16x8 kfv = *reinterpret_cast<const bf16x8*>(&Kb[krow + kc * 32 + c0]);
          sacc[nt] = __builtin_amdgcn_mfma_f32_16x16x32_bf16(qf[kc], kfv, sacc[nt], 0, 0, 0);
        }
      }

      // causal mask + online softmax (D layout: row=(lane>>4)*4+r, col=lane&15)
      const int rowbase = q0 + rg * 16 + (lane >> 4) * 4;
      float pv[2][4];
      float pmax[4] = {-1e30f, -1e30f, -1e30f, -1e30f};
#pragma unroll
      for (int nt = 0; nt < 2; ++nt) {
        const int s = s0j + nt * 16 + (lane & 15);
#pragma unroll
        for (int r = 0; r < 4; ++r) {
          float v = (s <= rowbase + r) ? sacc[nt][r] : -1e30f;
          pv[nt][r] = v;
          pmax[r] = fmaxf(pmax[r], v);
        }
      }
#pragma unroll
      for (int r = 0; r < 4; ++r) {
        float m = pmax[r];
        m = fmaxf(m, __shfl_xor(m, 1));
        m = fmaxf(m, __shfl_xor(m, 2));
        m = fmaxf(m, __shfl_xor(m, 4));
        m = fmaxf(m, __shfl_xor(m, 8));
        float mnew = fmaxf(mrow[r], m);
        float f = __expf(mrow[r] - mnew);
        mrow[r] = mnew;
        float ps = 0.f;
#pragma unroll
        for (int nt = 0; nt < 2; ++nt) {
          float p = __expf(pv[nt][r] - mnew);
          pv[nt][r] = p;
          ps += p;
        }
        ps += __shfl_xor(ps, 1);
        ps += __shfl_xor(ps, 2);
        ps += __shfl_xor(ps, 4);
        ps += __shfl_xor(ps, 8);
        lrow[r] = lrow[r] * f + ps;
#pragma unroll
        for (int n = 0; n < 8; ++n) o[n][r] *= f;
      }

      // P: D layout -> A layout via per-wave LDS round-trip (bf16)
#pragma unroll
      for (int nt = 0; nt < 2; ++nt)
#pragma unroll
        for (int r = 0; r < 4; ++r)
          Pl[wid][(lane >> 4) * 4 + r][nt * 16 + (lane & 15)] = f2bf(pv[nt][r]);
      bf16x8 pf = *reinterpret_cast<const bf16x8*>(&Pl[wid][lane & 15][(lane >> 4) * 8]);

      // O += P V : V B-frags from swizzled V^T LDS
#pragma unroll
      for (int n = 0; n < 8; ++n) {
        const int d = n * 16 + (lane & 15);
        const int gidx = kp * 4 + (lane >> 4);
        bf16x8 vf = *reinterpret_cast<const bf16x8*>(&Vt[d][(((gidx ^ (d >> 3)) & 15) << 3)]);
        o[n] = __builtin_amdgcn_mfma_f32_16x16x32_bf16(pf, vf, o[n], 0, 0, 0);
      }
    }
  }

  // ---- merge 4 KV-partials per row group (two phases, reusing Vt as f32 Om) ----
  float* Om = reinterpret_cast<float*>(&Vt[0][0]);  // [4][16][132]
  for (int ph = 0; ph < 2; ++ph) {
    __syncthreads();
    if (rg == ph) {
#pragma unroll
      for (int n = 0; n < 8; ++n)
#pragma unroll
        for (int r = 0; r < 4; ++r)
          Om[(kp * 16 + (lane >> 4) * 4 + r) * 132 + n * 16 + (lane & 15)] = o[n][r];
      if ((lane & 15) == 0)
#pragma unroll
        for (int r = 0; r < 4; ++r) {
          Ml[wid][(lane >> 4) * 4 + r][0] = mrow[r];
          Ml[wid][(lane >> 4) * 4 + r][1] = lrow[r];
        }
    }
    __syncthreads();
    if (rg == ph) {
      const int d = kp * 32 + (lane & 31);
      const int r0 = (lane >> 5) * 8;
#pragma unroll
      for (int rr = 0; rr < 8; ++rr) {
        int row = r0 + rr;
        float m0 = Ml[ph * 4 + 0][row][0], m1 = Ml[ph * 4 + 1][row][0];
        float m2 = Ml[ph * 4 + 2][row][0], m3 = Ml[ph * 4 + 3][row][0];
        float ms = fmaxf(fmaxf(m0, m1), fmaxf(m2, m3));
        float e0 = __expf(m0 - ms), e1 = __expf(m1 - ms);
        float e2 = __expf(m2 - ms), e3 = __expf(m3 - ms);
        float ls = Ml[ph * 4 + 0][row][1] * e0 + Ml[ph * 4 + 1][row][1] * e1 +
                   Ml[ph * 4 + 2][row][1] * e2 + Ml[ph * 4 + 3][row][1] * e3;
        float ov = Om[(0 * 16 + row) * 132 + d] * e0 + Om[(1 * 16 + row) * 132 + d] * e1 +
                   Om[(2 * 16 + row) * 132 + d] * e2 + Om[(3 * 16 + row) * 132 + d] * e3;
        Out[((size_t)b * Tn + q0 + ph * 16 + row) * DKn + d] = ov / ls;
      }
    }
  }
}

extern "C" void kernel_launch(void* const* d_in, const int* in_sizes, int n_in,
                              void* d_out, int out_size, void* d_ws, size_t ws_size,
                              hipStream_t stream) {
  const float* x  = (const float*)d_in[0];
  const float* Wq = (const float*)d_in[1];
  const float* Wk = (const float*)d_in[2];
  const float* Wv = (const float*)d_in[3];
  float* out = (float*)d_out;

  unsigned short* ws = (unsigned short*)d_ws;
  unsigned short* Xb = ws;                                   // 16384*1024
  unsigned short* Wb = Xb + (size_t)16384 * 1024;            // 3*128*1024
  unsigned short* Qw = Wb + (size_t)3 * 128 * 1024;          // 16384*128
  unsigned short* Kw = Qw + (size_t)16384 * 128;
  unsigned short* Vw = Kw + (size_t)16384 * 128;

  cvt_all<<<2048, 256, 0, stream>>>(x, Wq, Wk, Wv, Xb, Wb);
  qkv_proj<<<dim3(128, 3), 256, 0, stream>>>(Xb, Wb, Qw, Kw, Vw);
  attn<<<dim3(64, 8), 512, 0, stream>>>(Qw, Kw, Vw, out);
}

// Round 5
// 195.697 us; speedup vs baseline: 1.5606x; 1.3588x over previous
//
#include <hip/hip_runtime.h>
#include <hip/hip_bf16.h>

#define DEV static __device__ __forceinline__

typedef __attribute__((ext_vector_type(8))) short bf16x8;          // 8 bf16 (4 VGPRs)
typedef __attribute__((ext_vector_type(8))) unsigned short u16x8;  // raw 16B chunk
typedef __attribute__((ext_vector_type(4))) float f32x4;

constexpr int Bn = 8, Tn = 2048, DMn = 1024, DKn = 128;

DEV unsigned short f2bf(float f) {
  union { float f; unsigned u; } c; c.f = f;
  unsigned u = c.u;
  unsigned r = (u + 0x7fffu + ((u >> 16) & 1u)) >> 16;  // RNE
  return (unsigned short)r;
}

DEV void gload_lds16(const void* g, void* l) {
  __builtin_amdgcn_global_load_lds(
      (const __attribute__((address_space(1))) void*)g,
      (__attribute__((address_space(3))) void*)l, 16, 0, 0);
}

// ---------------- fp32 -> bf16 convert: x + 3 weights in ONE launch ----------------
__global__ void cvt_all(const float* __restrict__ x,  const float* __restrict__ wq,
                        const float* __restrict__ wk, const float* __restrict__ wv,
                        unsigned short* __restrict__ Xb, unsigned short* __restrict__ Wb) {
  constexpr int NX = 16384 * 1024 / 4;  // float4 chunks of x
  constexpr int NW = 131072 / 4;        // float4 chunks per W
  const int total = NX + 3 * NW;
  const int stride = gridDim.x * blockDim.x;
  for (int i = blockIdx.x * blockDim.x + threadIdx.x; i < total; i += stride) {
    const float* src; unsigned short* dst; int off;
    if (i < NX) { src = x; dst = Xb; off = i; }
    else {
      int j = i - NX; int w = j >> 15; off = j & (NW - 1);
      src = (w == 0) ? wq : (w == 1) ? wk : wv;
      dst = Wb + (size_t)w * 131072;
    }
    float4 v = *reinterpret_cast<const float4*>(src + (size_t)off * 4);
    ushort4 o;
    o.x = f2bf(v.x); o.y = f2bf(v.y); o.z = f2bf(v.z); o.w = f2bf(v.w);
    *reinterpret_cast<ushort4*>(dst + (size_t)off * 4) = o;
  }
}

// ---------------- QKV projection: C[m][n] = sum_k X[m][k] * W[n][k] ----------------
// 128x128 tile, BK=64, 4 waves (2x2). global_load_lds(16B) staging with
// source-side XOR swizzle (granule c8 ^= row&7): linear LDS dest, swizzled
// frag reads -> bank-conflict-free ds_read_b128 (T2 / rule #21).
__global__ __launch_bounds__(256, 4) void qkv_proj(
    const unsigned short* __restrict__ X,   // [16384][1024] bf16
    const unsigned short* __restrict__ W3,  // [3][128][1024] bf16
    unsigned short* __restrict__ Q,
    unsigned short* __restrict__ K,
    unsigned short* __restrict__ V) {
  constexpr int BK = 64;
  __shared__ __align__(16) unsigned short Al[128 * BK];
  __shared__ __align__(16) unsigned short Bl[128 * BK];
  const int g = blockIdx.y;
  const int m0 = blockIdx.x * 128;
  const unsigned short* Wg = W3 + (size_t)g * 128 * 1024;
  unsigned short* Out = (g == 0) ? Q : (g == 1) ? K : V;
  const float scale = (g == 0) ? 0.08838834764831845f : 1.0f;  // 1/sqrt(128) folded into Q

  const int tid = threadIdx.x;
  const int lane = tid & 63;
  const int wid = tid >> 6;
  const int wm = wid >> 1;
  const int wn = wid & 1;

  f32x4 acc[4][4] = {};

  for (int k0 = 0; k0 < DMn; k0 += BK) {
    __syncthreads();
#pragma unroll
    for (int it = 0; it < 4; ++it) {
      const int chbase = it * 256 + (tid & ~63);  // wave-uniform chunk base
      const int ch = chbase + lane;               // this lane's 16B chunk
      const int row = ch >> 3;
      const int sc8 = (ch & 7) ^ (row & 7);       // pre-swizzled source granule
      gload_lds16(&X[(size_t)(m0 + row) * DMn + k0 + sc8 * 8], &Al[chbase * 8]);
      gload_lds16(&Wg[(size_t)row * DMn + k0 + sc8 * 8], &Bl[chbase * 8]);
    }
    __syncthreads();  // compiler emits vmcnt(0) drain here
#pragma unroll
    for (int kk = 0; kk < 2; ++kk) {
      const int lrow = lane & 15;
      const int gr = kk * 4 + (lane >> 4);  // k-granule index (8 elems)
      bf16x8 af[4], bfr[4];
#pragma unroll
      for (int mf = 0; mf < 4; ++mf) {
        const int row = wm * 64 + mf * 16 + lrow;
        af[mf] = *reinterpret_cast<const bf16x8*>(&Al[row * BK + ((gr ^ (row & 7)) * 8)]);
      }
#pragma unroll
      for (int nf = 0; nf < 4; ++nf) {
        const int row = wn * 64 + nf * 16 + lrow;
        bfr[nf] = *reinterpret_cast<const bf16x8*>(&Bl[row * BK + ((gr ^ (row & 7)) * 8)]);
      }
#pragma unroll
      for (int mf = 0; mf < 4; ++mf)
#pragma unroll
        for (int nf = 0; nf < 4; ++nf)
          acc[mf][nf] = __builtin_amdgcn_mfma_f32_16x16x32_bf16(af[mf], bfr[nf], acc[mf][nf], 0, 0, 0);
    }
  }
#pragma unroll
  for (int mf = 0; mf < 4; ++mf)
#pragma unroll
    for (int nf = 0; nf < 4; ++nf)
#pragma unroll
      for (int r = 0; r < 4; ++r) {
        int m = m0 + wm * 64 + mf * 16 + (lane >> 4) * 4 + r;
        int n = wn * 64 + nf * 16 + (lane & 15);
        Out[(size_t)m * DKn + n] = f2bf(acc[mf][nf][r] * scale);
      }
}

// ---------------- causal flash attention, balanced + pipelined ----------------
// block = (32 Q-rows, one batch), 8 waves = 2 row-groups x 4-way KV split.
// Complement pairing: co-resident blocks (x,b) and (x,b+4) get t=63-x and t=x
// so each CU's total work ~= uniform. V staged double-buffered: regs loaded one
// iter ahead (T14), scatter-write -> ONE barrier -> compute.
__global__ __launch_bounds__(512, 4) void attn(
    const unsigned short* __restrict__ Qg,
    const unsigned short* __restrict__ Kg,
    const unsigned short* __restrict__ Vg,
    float* __restrict__ Out) {
  const int b = blockIdx.y;
  const int x = blockIdx.x;
  const int t = (b < 4) ? (63 - x) : x;   // complement pairing across the two dispatch halves
  const int q0 = t * 32;
  const int tid = threadIdx.x;
  const int lane = tid & 63;
  const int wid = tid >> 6;               // 0..7
  const int rg = wid >> 2;                // row group (16 rows each)
  const int kp = wid & 3;                 // KV parity
  const int nb = t + 1;                   // 32-wide KV blocks in causal range
  const int nsuper = (nb + 3) >> 2;

  const unsigned short* Qb = Qg + (size_t)b * Tn * DKn;
  const unsigned short* Kb = Kg + (size_t)b * Tn * DKn;
  const unsigned short* Vb = Vg + (size_t)b * Tn * DKn;

  __shared__ __align__(16) unsigned short Vt[2][128][136];  // V^T dbuf, s-group swizzled (69.6KB)
  __shared__ __align__(16) unsigned short Pl[8][16][40];    // per-wave P round-trip
  __shared__ float Ml[8][16][2];                            // per-wave (m,l) for merge

  // Q fragments (pre-scaled by 1/sqrt(128) at projection)
  bf16x8 qf[4];
  {
    const int qrow = q0 + rg * 16 + (lane & 15);
    const int c0 = (lane >> 4) * 8;
#pragma unroll
    for (int c = 0; c < 4; ++c)
      qf[c] = *reinterpret_cast<const bf16x8*>(&Qb[(size_t)qrow * DKn + c * 32 + c0]);
  }

  f32x4 o[8] = {};
  float mrow[4] = {-1e30f, -1e30f, -1e30f, -1e30f};
  float lrow[4] = {0.f, 0.f, 0.f, 0.f};

  // V staging coords (fixed per thread): chunk c = k*512 + tid -> s = c>>4, d0 = (c&15)*8
  u16x8 vreg[4];
#pragma unroll
  for (int k = 0; k < 4; ++k) {
    int c = k * 512 + tid;
    vreg[k] = *reinterpret_cast<const u16x8*>(&Vb[(size_t)(c >> 4) * DKn + (c & 15) * 8]);
  }

  for (int siter = 0; siter < nsuper; ++siter) {
    const int cur = siter & 1;
    // scatter-write current V chunk (swizzle: col = (((s>>3)^(d>>3))&15)*8 + (s&7))
#pragma unroll
    for (int k = 0; k < 4; ++k) {
      int c = k * 512 + tid;
      int s = c >> 4;
      int d0 = (c & 15) * 8;
#pragma unroll
      for (int jj = 0; jj < 8; ++jj) {
        int d = d0 + jj;
        int col = ((((s >> 3) ^ (d >> 3)) & 15) << 3) | (s & 7);
        Vt[cur][d][col] = (unsigned short)vreg[k][jj];
      }
    }
    // issue next chunk's global loads (latency hides under this iter's compute)
    if (siter + 1 < nsuper) {
      const int sbase = (siter + 1) * 128;
#pragma unroll
      for (int k = 0; k < 4; ++k) {
        int c = k * 512 + tid;
        vreg[k] = *reinterpret_cast<const u16x8*>(&Vb[(size_t)(sbase + (c >> 4)) * DKn + (c & 15) * 8]);
      }
    }
    __syncthreads();  // writes visible; single barrier per iter

    const int j = siter * 4 + kp;
    if (j < nb) {
      const int s0j = j * 32;
      // S = Q K^T (16 rows x 32 KV), K B-frags from global (L2-resident)
      f32x4 sacc[2] = {};
      const int c0 = (lane >> 4) * 8;
#pragma unroll
      for (int nt = 0; nt < 2; ++nt) {
        const size_t krow = (size_t)(s0j + nt * 16 + (lane & 15)) * DKn;
#pragma unroll
        for (int kc = 0; kc < 4; ++kc) {
          bf16x8 kfv = *reinterpret_cast<const bf16x8*>(&Kb[krow + kc * 32 + c0]);
          sacc[nt] = __builtin_amdgcn_mfma_f32_16x16x32_bf16(qf[kc], kfv, sacc[nt], 0, 0, 0);
        }
      }

      // causal mask + online softmax (D layout: row=(lane>>4)*4+r, col=lane&15)
      const int rowbase = q0 + rg * 16 + (lane >> 4) * 4;
      float pv[2][4];
      float pmax[4] = {-1e30f, -1e30f, -1e30f, -1e30f};
#pragma unroll
      for (int nt = 0; nt < 2; ++nt) {
        const int s = s0j + nt * 16 + (lane & 15);
#pragma unroll
        for (int r = 0; r < 4; ++r) {
          float v = (s <= rowbase + r) ? sacc[nt][r] : -1e30f;
          pv[nt][r] = v;
          pmax[r] = fmaxf(pmax[r], v);
        }
      }
#pragma unroll
      for (int r = 0; r < 4; ++r) {
        float m = pmax[r];
        m = fmaxf(m, __shfl_xor(m, 1));
        m = fmaxf(m, __shfl_xor(m, 2));
        m = fmaxf(m, __shfl_xor(m, 4));
        m = fmaxf(m, __shfl_xor(m, 8));
        float mnew = fmaxf(mrow[r], m);
        float f = __expf(mrow[r] - mnew);
        mrow[r] = mnew;
        float ps = 0.f;
#pragma unroll
        for (int nt = 0; nt < 2; ++nt) {
          float p = __expf(pv[nt][r] - mnew);
          pv[nt][r] = p;
          ps += p;
        }
        ps += __shfl_xor(ps, 1);
        ps += __shfl_xor(ps, 2);
        ps += __shfl_xor(ps, 4);
        ps += __shfl_xor(ps, 8);
        lrow[r] = lrow[r] * f + ps;
#pragma unroll
        for (int n = 0; n < 8; ++n) o[n][r] *= f;
      }

      // P: D layout -> A layout via per-wave LDS round-trip (bf16)
#pragma unroll
      for (int nt = 0; nt < 2; ++nt)
#pragma unroll
        for (int r = 0; r < 4; ++r)
          Pl[wid][(lane >> 4) * 4 + r][nt * 16 + (lane & 15)] = f2bf(pv[nt][r]);
      bf16x8 pf = *reinterpret_cast<const bf16x8*>(&Pl[wid][lane & 15][(lane >> 4) * 8]);

      // O += P V : V B-frags from swizzled V^T LDS
#pragma unroll
      for (int n = 0; n < 8; ++n) {
        const int d = n * 16 + (lane & 15);
        const int gidx = kp * 4 + (lane >> 4);
        bf16x8 vf = *reinterpret_cast<const bf16x8*>(&Vt[cur][d][(((gidx ^ (d >> 3)) & 15) << 3)]);
        o[n] = __builtin_amdgcn_mfma_f32_16x16x32_bf16(pf, vf, o[n], 0, 0, 0);
      }
    }
  }

  // ---- merge 4 KV-partials per row group (two phases, reusing Vt[0] as f32 Om) ----
  float* Om = reinterpret_cast<float*>(&Vt[0][0][0]);  // [4][16][132]
  for (int ph = 0; ph < 2; ++ph) {
    __syncthreads();
    if (rg == ph) {
#pragma unroll
      for (int n = 0; n < 8; ++n)
#pragma unroll
        for (int r = 0; r < 4; ++r)
          Om[(kp * 16 + (lane >> 4) * 4 + r) * 132 + n * 16 + (lane & 15)] = o[n][r];
      if ((lane & 15) == 0)
#pragma unroll
        for (int r = 0; r < 4; ++r) {
          Ml[wid][(lane >> 4) * 4 + r][0] = mrow[r];
          Ml[wid][(lane >> 4) * 4 + r][1] = lrow[r];
        }
    }
    __syncthreads();
    if (rg == ph) {
      const int d = kp * 32 + (lane & 31);
      const int r0 = (lane >> 5) * 8;
#pragma unroll
      for (int rr = 0; rr < 8; ++rr) {
        int row = r0 + rr;
        float m0 = Ml[ph * 4 + 0][row][0], m1 = Ml[ph * 4 + 1][row][0];
        float m2 = Ml[ph * 4 + 2][row][0], m3 = Ml[ph * 4 + 3][row][0];
        float ms = fmaxf(fmaxf(m0, m1), fmaxf(m2, m3));
        float e0 = __expf(m0 - ms), e1 = __expf(m1 - ms);
        float e2 = __expf(m2 - ms), e3 = __expf(m3 - ms);
        float ls = Ml[ph * 4 + 0][row][1] * e0 + Ml[ph * 4 + 1][row][1] * e1 +
                   Ml[ph * 4 + 2][row][1] * e2 + Ml[ph * 4 + 3][row][1] * e3;
        float ov = Om[(0 * 16 + row) * 132 + d] * e0 + Om[(1 * 16 + row) * 132 + d] * e1 +
                   Om[(2 * 16 + row) * 132 + d] * e2 + Om[(3 * 16 + row) * 132 + d] * e3;
        Out[((size_t)b * Tn + q0 + ph * 16 + row) * DKn + d] = ov / ls;
      }
    }
  }
}

extern "C" void kernel_launch(void* const* d_in, const int* in_sizes, int n_in,
                              void* d_out, int out_size, void* d_ws, size_t ws_size,
                              hipStream_t stream) {
  const float* x  = (const float*)d_in[0];
  const float* Wq = (const float*)d_in[1];
  const float* Wk = (const float*)d_in[2];
  const float* Wv = (const float*)d_in[3];
  float* out = (float*)d_out;

  unsigned short* ws = (unsigned short*)d_ws;
  unsigned short* Xb = ws;                                   // 16384*1024
  unsigned short* Wb = Xb + (size_t)16384 * 1024;            // 3*128*1024
  unsigned short* Qw = Wb + (size_t)3 * 128 * 1024;          // 16384*128
  unsigned short* Kw = Qw + (size_t)16384 * 128;
  unsigned short* Vw = Kw + (size_t)16384 * 128;

  cvt_all<<<2048, 256, 0, stream>>>(x, Wq, Wk, Wv, Xb, Wb);
  qkv_proj<<<dim3(128, 3), 256, 0, stream>>>(Xb, Wb, Qw, Kw, Vw);
  attn<<<dim3(64, 8), 512, 0, stream>>>(Qw, Kw, Vw, out);
}

// Round 6
// 181.907 us; speedup vs baseline: 1.6789x; 1.0758x over previous
//
#include <hip/hip_runtime.h>
#include <hip/hip_bf16.h>

#define DEV static __device__ __forceinline__

typedef __attribute__((ext_vector_type(8))) short bf16x8;          // 8 bf16 (4 VGPRs)
typedef __attribute__((ext_vector_type(8))) unsigned short u16x8;  // raw 16B chunk
typedef __attribute__((ext_vector_type(4))) float f32x4;

constexpr int Bn = 8, Tn = 2048, DMn = 1024, DKn = 128;

DEV unsigned short f2bf(float f) {
  union { float f; unsigned u; } c; c.f = f;
  unsigned u = c.u;
  unsigned r = (u + 0x7fffu + ((u >> 16) & 1u)) >> 16;  // RNE
  return (unsigned short)r;
}

DEV void gload_lds16(const void* g, void* l) {
  __builtin_amdgcn_global_load_lds(
      (const __attribute__((address_space(1))) void*)g,
      (__attribute__((address_space(3))) void*)l, 16, 0, 0);
}

// ---------------- fp32 -> bf16 convert, weights only (x handled in-GEMM) ----------------
__global__ void cvt_w(const float* __restrict__ wq, const float* __restrict__ wk,
                      const float* __restrict__ wv, unsigned short* __restrict__ Wb) {
  // 3 * 131072 elems = 98304 float4 chunks; grid 384 x 256 = exactly one chunk/thread
  const int i = blockIdx.x * 256 + threadIdx.x;
  const int w = i >> 15;            // 32768 chunks per weight
  const int off = i & 32767;
  const float* src = (w == 0) ? wq : (w == 1) ? wk : wv;
  float4 v = reinterpret_cast<const float4*>(src)[off];
  ushort4 o;
  o.x = f2bf(v.x); o.y = f2bf(v.y); o.z = f2bf(v.z); o.w = f2bf(v.w);
  reinterpret_cast<ushort4*>(Wb + (size_t)w * 131072)[off] = o;
}

// ---------------- fused QKV projection ----------------
// One GEMM: C[16384][384] = X[16384][1024] (fp32, converted in staging) x W3^T.
// M-tile 64, grid 256, 8 waves (2m x 4n), each wave 32x96 = 2x6 frags.
// A reg-staged with next-iter prefetch (fp32->bf16, swizzled ds_write);
// B via global_load_lds(16B) with source-side XOR swizzle (rule #21).
// Epilogue: Q (scaled), K direct; V written TRANSPOSED to global via in-LDS transpose.
__global__ __launch_bounds__(512, 2) void qkv_proj(
    const float* __restrict__ X,            // [16384][1024] fp32
    const unsigned short* __restrict__ W3,  // [384][1024] bf16 (Wq|Wk|Wv)
    unsigned short* __restrict__ Q,         // [16384][128]
    unsigned short* __restrict__ K,         // [16384][128]
    unsigned short* __restrict__ VT) {      // [8][128][2048]
  __shared__ __align__(16) unsigned short Al[64 * 64];    // 8 KB
  __shared__ __align__(16) unsigned short Bl[384 * 64];   // 48 KB (reused as V^T tile)
  const int m0 = blockIdx.x * 64;
  const int tid = threadIdx.x;
  const int lane = tid & 63;
  const int wid = tid >> 6;
  const int wm = wid >> 2;   // 0..1
  const int wn = wid & 3;    // 0..3

  f32x4 acc[2][6] = {};

  // A-staging coords: chunk = tid -> row 0..63, granule 0..7 (8 bf16 = 16B)
  const int arow = tid >> 3;
  const int ag8 = tid & 7;
  const float4* x4 = reinterpret_cast<const float4*>(X + (size_t)(m0 + arow) * DMn);

  float4 u = x4[ag8 * 2];
  float4 v = x4[ag8 * 2 + 1];

  for (int k0 = 0; k0 < DMn; k0 += 64) {
    u16x8 aw;
    aw[0] = f2bf(u.x); aw[1] = f2bf(u.y); aw[2] = f2bf(u.z); aw[3] = f2bf(u.w);
    aw[4] = f2bf(v.x); aw[5] = f2bf(v.y); aw[6] = f2bf(v.z); aw[7] = f2bf(v.w);
    __syncthreads();  // previous compute done; LDS safe to overwrite
    *reinterpret_cast<u16x8*>(&Al[arow * 64 + ((ag8 ^ (arow & 7)) << 3)]) = aw;
#pragma unroll
    for (int it = 0; it < 6; ++it) {
      const int chbase = it * 512 + (tid & ~63);  // wave-uniform chunk base
      const int ch = chbase + lane;
      const int row = ch >> 3;                    // 0..383
      const int sc8 = (ch & 7) ^ (row & 7);       // pre-swizzled source granule
      gload_lds16(&W3[(size_t)row * DMn + k0 + sc8 * 8], &Bl[chbase * 8]);
    }
    __syncthreads();  // staging visible (vmcnt drain)
    if (k0 + 64 < DMn) {  // prefetch next A chunk; latency hides under compute
      u = x4[((k0 + 64) >> 2) + ag8 * 2];
      v = x4[((k0 + 64) >> 2) + ag8 * 2 + 1];
    }
#pragma unroll
    for (int kk = 0; kk < 2; ++kk) {
      const int lrow = lane & 15;
      const int gr = kk * 4 + (lane >> 4);
      bf16x8 af[2], bfr[6];
#pragma unroll
      for (int mf = 0; mf < 2; ++mf) {
        const int row = wm * 32 + mf * 16 + lrow;
        af[mf] = *reinterpret_cast<const bf16x8*>(&Al[row * 64 + ((gr ^ (row & 7)) << 3)]);
      }
#pragma unroll
      for (int nf = 0; nf < 6; ++nf) {
        const int row = wn * 96 + nf * 16 + lrow;
        bfr[nf] = *reinterpret_cast<const bf16x8*>(&Bl[row * 64 + ((gr ^ (row & 7)) << 3)]);
      }
#pragma unroll
      for (int mf = 0; mf < 2; ++mf)
#pragma unroll
        for (int nf = 0; nf < 6; ++nf)
          acc[mf][nf] = __builtin_amdgcn_mfma_f32_16x16x32_bf16(af[mf], bfr[nf], acc[mf][nf], 0, 0, 0);
    }
  }
  __syncthreads();  // all frag reads done; Bl reusable as V^T tile

  // epilogue: D layout col=lane&15, row=(lane>>4)*4+r  [measured m89]
  unsigned short (*Vt_l)[72] = reinterpret_cast<unsigned short(*)[72]>(&Bl[0]);  // [128][72]
  const int bidx = m0 >> 11;
  const int mb = m0 & 2047;
#pragma unroll
  for (int mf = 0; mf < 2; ++mf)
#pragma unroll
    for (int nf = 0; nf < 6; ++nf) {
      const int n = wn * 96 + nf * 16 + (lane & 15);
#pragma unroll
      for (int r = 0; r < 4; ++r) {
        const int m = m0 + wm * 32 + mf * 16 + (lane >> 4) * 4 + r;
        const float val = acc[mf][nf][r];
        if (n < 128)       Q[(size_t)m * DKn + n] = f2bf(val * 0.08838834764831845f);
        else if (n < 256)  K[(size_t)m * DKn + (n - 128)] = f2bf(val);
        else               Vt_l[n - 256][m - m0] = f2bf(val);  // transpose in LDS
      }
    }
  __syncthreads();
  // store V^T tile: 128 rows x 64 bf16, coalesced 16B chunks
#pragma unroll
  for (int it = 0; it < 2; ++it) {
    const int ch = it * 512 + tid;   // 0..1023
    const int row = ch >> 3;
    const int g8 = ch & 7;
    u16x8 w = *reinterpret_cast<const u16x8*>(&Vt_l[row][g8 * 8]);
    *reinterpret_cast<u16x8*>(&VT[(size_t)bidx * DKn * Tn + (size_t)row * Tn + mb + g8 * 8]) = w;
  }
}

// ---------------- causal flash attention: barrier-free main loop ----------------
// block = (32 Q-rows, one batch), 8 waves = 2 row-groups x 4-way KV split.
// K and V^T fragments stream from global (L2-resident); no LDS staging, no
// barriers until the final merge. Complement pairing balances per-CU work.
__global__ __launch_bounds__(512, 4) void attn(
    const unsigned short* __restrict__ Qg,
    const unsigned short* __restrict__ Kg,
    const unsigned short* __restrict__ VTg,  // [8][128][2048]
    float* __restrict__ Out) {
  const int b = blockIdx.y;
  const int x = blockIdx.x;
  const int t = (b < 4) ? (63 - x) : x;   // complement pairing
  const int q0 = t * 32;
  const int lane = threadIdx.x & 63;
  const int wid = threadIdx.x >> 6;       // 0..7
  const int rg = wid >> 2;                // row group (16 rows)
  const int kp = wid & 3;                 // KV split index
  const int nb = t + 1;                   // 32-wide KV blocks in causal range

  const unsigned short* Qb = Qg + (size_t)b * Tn * DKn;
  const unsigned short* Kb = Kg + (size_t)b * Tn * DKn;
  const unsigned short* Vt = VTg + (size_t)b * DKn * Tn;

  __shared__ __align__(16) unsigned short Pl[8][16][40];  // per-wave P round-trip (10 KB)
  __shared__ float Ml[8][16][2];                          // (m,l) for merge
  __shared__ float Om[4][16][132];                        // merge buffer (33 KB)

  bf16x8 qf[4];
  {
    const int qrow = q0 + rg * 16 + (lane & 15);
    const int c0 = (lane >> 4) * 8;
#pragma unroll
    for (int c = 0; c < 4; ++c)
      qf[c] = *reinterpret_cast<const bf16x8*>(&Qb[(size_t)qrow * DKn + c * 32 + c0]);
  }

  f32x4 o[8] = {};
  float mrow[4] = {-1e30f, -1e30f, -1e30f, -1e30f};
  float lrow[4] = {0.f, 0.f, 0.f, 0.f};

  for (int j = kp; j < nb; j += 4) {
    const int s0j = j * 32;
    // S = Q K^T (16 rows x 32 KV), K B-frags from global
    f32x4 sacc[2] = {};
    const int c0 = (lane >> 4) * 8;
#pragma unroll
    for (int nt = 0; nt < 2; ++nt) {
      const size_t krow = (size_t)(s0j + nt * 16 + (lane & 15)) * DKn;
#pragma unroll
      for (int kc = 0; kc < 4; ++kc) {
        bf16x8 kfv = *reinterpret_cast<const bf16x8*>(&Kb[krow + kc * 32 + c0]);
        sacc[nt] = __builtin_amdgcn_mfma_f32_16x16x32_bf16(qf[kc], kfv, sacc[nt], 0, 0, 0);
      }
    }

    // causal mask + online softmax (D layout: row=(lane>>4)*4+r, col=lane&15)
    const int rowbase = q0 + rg * 16 + (lane >> 4) * 4;
    float pv[2][4];
    float pmax[4] = {-1e30f, -1e30f, -1e30f, -1e30f};
#pragma unroll
    for (int nt = 0; nt < 2; ++nt) {
      const int s = s0j + nt * 16 + (lane & 15);
#pragma unroll
      for (int r = 0; r < 4; ++r) {
        float vv = (s <= rowbase + r) ? sacc[nt][r] : -1e30f;
        pv[nt][r] = vv;
        pmax[r] = fmaxf(pmax[r], vv);
      }
    }
#pragma unroll
    for (int r = 0; r < 4; ++r) {
      float m = pmax[r];
      m = fmaxf(m, __shfl_xor(m, 1));
      m = fmaxf(m, __shfl_xor(m, 2));
      m = fmaxf(m, __shfl_xor(m, 4));
      m = fmaxf(m, __shfl_xor(m, 8));
      float mnew = fmaxf(mrow[r], m);
      float f = __expf(mrow[r] - mnew);
      mrow[r] = mnew;
      float ps = 0.f;
#pragma unroll
      for (int nt = 0; nt < 2; ++nt) {
        float p = __expf(pv[nt][r] - mnew);
        pv[nt][r] = p;
        ps += p;
      }
      ps += __shfl_xor(ps, 1);
      ps += __shfl_xor(ps, 2);
      ps += __shfl_xor(ps, 4);
      ps += __shfl_xor(ps, 8);
      lrow[r] = lrow[r] * f + ps;
#pragma unroll
      for (int n = 0; n < 8; ++n) o[n][r] *= f;
    }

    // P: D layout -> A layout via wave-private LDS round-trip (no barrier needed)
#pragma unroll
    for (int nt = 0; nt < 2; ++nt)
#pragma unroll
      for (int r = 0; r < 4; ++r)
        Pl[wid][(lane >> 4) * 4 + r][nt * 16 + (lane & 15)] = f2bf(pv[nt][r]);
    bf16x8 pf = *reinterpret_cast<const bf16x8*>(&Pl[wid][lane & 15][(lane >> 4) * 8]);

    // O += P V : V^T B-frags straight from global (contiguous 16B, L2-resident)
#pragma unroll
    for (int n = 0; n < 8; ++n) {
      bf16x8 vf = *reinterpret_cast<const bf16x8*>(
          &Vt[(size_t)(n * 16 + (lane & 15)) * Tn + s0j + (lane >> 4) * 8]);
      o[n] = __builtin_amdgcn_mfma_f32_16x16x32_bf16(pf, vf, o[n], 0, 0, 0);
    }
  }

  // ---- merge 4 KV-partials per row group ----
  __syncthreads();
  for (int ph = 0; ph < 2; ++ph) {
    if (ph) __syncthreads();
    if (rg == ph) {
#pragma unroll
      for (int n = 0; n < 8; ++n)
#pragma unroll
        for (int r = 0; r < 4; ++r)
          Om[kp][(lane >> 4) * 4 + r][n * 16 + (lane & 15)] = o[n][r];
      if ((lane & 15) == 0)
#pragma unroll
        for (int r = 0; r < 4; ++r) {
          Ml[wid][(lane >> 4) * 4 + r][0] = mrow[r];
          Ml[wid][(lane >> 4) * 4 + r][1] = lrow[r];
        }
    }
    __syncthreads();
    if (rg == ph) {
      const int d = kp * 32 + (lane & 31);
      const int r0 = (lane >> 5) * 8;
#pragma unroll
      for (int rr = 0; rr < 8; ++rr) {
        int row = r0 + rr;
        float m0 = Ml[ph * 4 + 0][row][0], m1 = Ml[ph * 4 + 1][row][0];
        float m2 = Ml[ph * 4 + 2][row][0], m3 = Ml[ph * 4 + 3][row][0];
        float ms = fmaxf(fmaxf(m0, m1), fmaxf(m2, m3));
        float e0 = __expf(m0 - ms), e1 = __expf(m1 - ms);
        float e2 = __expf(m2 - ms), e3 = __expf(m3 - ms);
        float ls = Ml[ph * 4 + 0][row][1] * e0 + Ml[ph * 4 + 1][row][1] * e1 +
                   Ml[ph * 4 + 2][row][1] * e2 + Ml[ph * 4 + 3][row][1] * e3;
        float ov = Om[0][row][d] * e0 + Om[1][row][d] * e1 +
                   Om[2][row][d] * e2 + Om[3][row][d] * e3;
        Out[((size_t)b * Tn + q0 + ph * 16 + row) * DKn + d] = ov / ls;
      }
    }
  }
}

extern "C" void kernel_launch(void* const* d_in, const int* in_sizes, int n_in,
                              void* d_out, int out_size, void* d_ws, size_t ws_size,
                              hipStream_t stream) {
  const float* x  = (const float*)d_in[0];
  const float* Wq = (const float*)d_in[1];
  const float* Wk = (const float*)d_in[2];
  const float* Wv = (const float*)d_in[3];
  float* out = (float*)d_out;

  unsigned short* ws = (unsigned short*)d_ws;
  unsigned short* Wb  = ws;                                  // 384*1024
  unsigned short* Qw  = Wb + (size_t)384 * 1024;             // 16384*128
  unsigned short* Kw  = Qw + (size_t)16384 * 128;            // 16384*128
  unsigned short* VTw = Kw + (size_t)16384 * 128;            // 8*128*2048

  cvt_w<<<384, 256, 0, stream>>>(Wq, Wk, Wv, Wb);
  qkv_proj<<<256, 512, 0, stream>>>(x, Wb, Qw, Kw, VTw);
  attn<<<dim3(64, 8), 512, 0, stream>>>(Qw, Kw, VTw, out);
}